// Round 11
// baseline (141.477 us; speedup 1.0000x reference)
//
#include <hip/hip_runtime.h>
#include <hip/hip_bf16.h>

// HeadC fused: grouped 1x1-conv projections (q,k,v) + causal softmax attention.
// B=4096, T=50, N_EMBED=600, HEAD_SIZE=100, CHUNK=6.
// R8: cross-batch software pipeline. Each block processes NB=8 batches with
// double-buffered LDS (q,k,vT); x loads for batch i+1 issued before batch i's
// scores/softmax/PV and consumed after (T14 async-STAGE). Raw s_barrier +
// lgkmcnt(0) only (no vmcnt drain) keeps prefetch loads in flight across
// barriers. P overlays the dead buffer's q region. Pads zeroed once per block.

#define BATCH 4096
#define TT 50
#define HH 100
#define CC 600

typedef __attribute__((ext_vector_type(8))) short short8;
typedef __attribute__((ext_vector_type(4))) short short4v;
typedef __attribute__((ext_vector_type(4))) float f32x4;
typedef unsigned short ushort_t;

constexpr int NTHR = 256;
constexpr int NWAVES = 4;
constexpr int NB = 8;                 // batches per block
constexpr int GRID = BATCH / NB;      // 512 -> exactly 2 blocks/CU
constexpr float kScale = 0.04082482904638630163f;  // 600^-0.5 (folded into q)

// LDS (ushort units): two proj buffers + spill pad = 39168 us = 78336 B.
//   buf b at b*19200:  q @ +0 [50][128] | k @ +6400 [50][128] | vT @ +12800 [100][64]
//   pad @ 38400 (768 us, zeroed) absorbs buf1.vT frag-row spill (rows 100..111).
// P[64][64] overlays the DEAD buffer's q region (written by scores, dead after PV,
// then overwritten by the next batch's q).
// Frag-spill audit: q rows 50..63 -> k region (finite); k rows 50..63 -> vT
// (finite); buf0.vT rows 100..111 -> buf1.q=P (finite, read-only in PV, junk
// contained to discarded h>=100 D-columns); buf1.vT rows 100..111 -> zero pad.
constexpr int BUF_US = 19200;
constexpr int RQ = 0, RK = 6400, RV = 12800;
constexpr int PAD_US = 38400;
constexpr int LDS_US = 39168;

__device__ __forceinline__ ushort_t f2bf(float f) {
    return __builtin_bit_cast(ushort_t, __float2bfloat16(f));
}
__device__ __forceinline__ float bf2f(ushort_t h) {
    return __uint_as_float(((unsigned)h) << 16);
}
// Barrier that does NOT drain vmcnt: LDS producer/consumer ordering only.
__device__ __forceinline__ void bar_lds() {
    asm volatile("s_waitcnt lgkmcnt(0)" ::: "memory");
    __builtin_amdgcn_s_barrier();
    asm volatile("" ::: "memory");
}

__global__ __launch_bounds__(NTHR, 2) void headc_fused(
    const float* __restrict__ x,
    const float* __restrict__ wq,
    const float* __restrict__ wk,
    const float* __restrict__ wv,
    float* __restrict__ out)
{
    __shared__ __align__(16) ushort_t lds[LDS_US];

    const int tid = threadIdx.x;
    const float* xblk = x + (size_t)blockIdx.x * NB * (TT * CC);
    float* oblk = out + (size_t)blockIdx.x * NB * (TT * HH);

    // proj thread mapping (fixed across batches): hp pinned -> weights in regs
    const int hp = tid % 50;
    const int c = tid / 50;                 // 0..5 (c==5 -> inactive in proj)
    const int h0 = hp * 2;
    const int nqd = (c >= 3) ? 2 : 3;       // qd set {c, c+5, c+10(<13)}
    const bool pactive = (tid < 250);

    // ---- once per block: zero K-pad regions + spill pad ----
    {
        const short8 z8 = {0, 0, 0, 0, 0, 0, 0, 0};
        const short4v z4 = {0, 0, 0, 0};
        for (int j = tid; j < 400; j += NTHR) {
            if (j < 200) {  // q/k cols 100..127 (logical granule 12-hi, 13..15)
                const int buf = (j >= 100) ? BUF_US : 0;
                const int arr = ((j / 50) & 1) ? RK : RQ;
                const int r = j % 50;
                const int base = buf + arr + r * 128;
                *reinterpret_cast<short4v*>(lds + base + ((12 ^ (r & 7)) << 3) + 4) = z4;
                *reinterpret_cast<short8*>(lds + base + ((13 ^ (r & 7)) << 3)) = z8;
                *reinterpret_cast<short8*>(lds + base + ((14 ^ (r & 7)) << 3)) = z8;
                *reinterpret_cast<short8*>(lds + base + ((15 ^ (r & 7)) << 3)) = z8;
            } else {        // vT cols 52..63 (granule 6-hi, 7)
                const int jj = j - 200;
                const int buf = (jj >= 100) ? BUF_US : 0;
                const int h = jj % 100;
                const int base = buf + RV + h * 64;
                *reinterpret_cast<short4v*>(lds + base + ((6 ^ (h & 7)) << 3) + 4) = z4;
                *reinterpret_cast<short8*>(lds + base + ((7 ^ (h & 7)) << 3)) = z8;
            }
        }
        for (int j = tid; j < 96; j += NTHR)
            *reinterpret_cast<short8*>(lds + PAD_US + j * 8) = z8;
    }

    // weights -> registers, once
    float4 w0, w1, w2, w3, w4, w5, w6, w7, w8;
    if (pactive) {
        w0 = *(const float4*)(wq + h0 * 6);
        w1 = *(const float4*)(wq + h0 * 6 + 4);
        w2 = *(const float4*)(wq + h0 * 6 + 8);
        w3 = *(const float4*)(wk + h0 * 6);
        w4 = *(const float4*)(wk + h0 * 6 + 4);
        w5 = *(const float4*)(wk + h0 * 6 + 8);
        w6 = *(const float4*)(wv + h0 * 6);
        w7 = *(const float4*)(wv + h0 * 6 + 4);
        w8 = *(const float4*)(wv + h0 * 6 + 8);
    }

    float4 xr[3][4][3];   // prefetched x for the next batch (static idx only)

    auto issue_x = [&](int bi) {
        if (pactive) {
            const float* xb = xblk + (size_t)bi * (TT * CC);
            #pragma unroll
            for (int u = 0; u < 3; ++u) {
                if (u < nqd) {
                    const int tb = (c + u * 5) * 4;
                    #pragma unroll
                    for (int r = 0; r < 4; ++r) {
                        const int tc = (tb + r < TT) ? (tb + r) : (TT - 1);
                        const float* xp = xb + tc * CC + h0 * 6;  // 48B/lane, coalesced
                        xr[u][r][0] = *(const float4*)xp;
                        xr[u][r][1] = *(const float4*)(xp + 4);
                        xr[u][r][2] = *(const float4*)(xp + 8);
                    }
                }
            }
        }
    };

    auto do_proj = [&](int base) {
        if (pactive) {
            #pragma unroll
            for (int u = 0; u < 3; ++u) {
                if (u < nqd) {
                    const int qd = c + u * 5;
                    const int tb = qd * 4;
                    short4v vp0 = {0, 0, 0, 0}, vp1 = {0, 0, 0, 0};
                    #pragma unroll
                    for (int r = 0; r < 4; ++r) {
                        const int t = tb + r;
                        const float4 xa = xr[u][r][0], xm = xr[u][r][1], xc = xr[u][r][2];
                        float q0 = xa.x*w0.x + xa.y*w0.y + xa.z*w0.z + xa.w*w0.w + xm.x*w1.x + xm.y*w1.y;
                        float q1 = xm.z*w1.z + xm.w*w1.w + xc.x*w2.x + xc.y*w2.y + xc.z*w2.z + xc.w*w2.w;
                        float k0 = xa.x*w3.x + xa.y*w3.y + xa.z*w3.z + xa.w*w3.w + xm.x*w4.x + xm.y*w4.y;
                        float k1 = xm.z*w4.z + xm.w*w4.w + xc.x*w5.x + xc.y*w5.y + xc.z*w5.z + xc.w*w5.w;
                        float v0 = xa.x*w6.x + xa.y*w6.y + xa.z*w6.z + xa.w*w6.w + xm.x*w7.x + xm.y*w7.y;
                        float v1 = xm.z*w7.z + xm.w*w7.w + xc.x*w8.x + xc.y*w8.y + xc.z*w8.z + xc.w*w8.w;
                        q0 *= kScale; q1 *= kScale;
                        if (t < TT) {
                            const int qg = (((h0 >> 3) ^ (t & 7)) << 3) + (h0 & 7);
                            *reinterpret_cast<unsigned*>(lds + base + RQ + t * 128 + qg) =
                                (unsigned)f2bf(q0) | ((unsigned)f2bf(q1) << 16);
                            *reinterpret_cast<unsigned*>(lds + base + RK + t * 128 + qg) =
                                (unsigned)f2bf(k0) | ((unsigned)f2bf(k1) << 16);
                            vp0[r] = (short)f2bf(v0);
                            vp1[r] = (short)f2bf(v1);
                        }
                    }
                    const int g = qd >> 1, half = (qd & 1) * 4;
                    *reinterpret_cast<short4v*>(lds + base + RV + h0 * 64 + ((g ^ (h0 & 7)) << 3) + half) = vp0;
                    *reinterpret_cast<short4v*>(lds + base + RV + (h0 + 1) * 64 + ((g ^ ((h0 + 1) & 7)) << 3) + half) = vp1;
                }
            }
        }
    };

    // ---- prologue: batch 0 unpipelined into buf0 ----
    issue_x(0);
    __builtin_amdgcn_sched_barrier(0);
    do_proj(0);

    const int wv_ = tid >> 6;
    const int lane = tid & 63;
    const int l15 = lane & 15, l4 = lane >> 4;

    #pragma unroll 2
    for (int i = 0; i < NB; ++i) {
        const int cur = (i & 1) * BUF_US;
        const int oth = BUF_US - cur;
        const int OP = oth + RQ;           // P overlays dead buffer's q

        // prefetch x for batch i+1 (stays in flight across all barriers below)
        if (i + 1 < NB) {
            issue_x(i + 1);
            __builtin_amdgcn_sched_barrier(0);
        }

        bar_lds();   // A: proj(bi) LDS-visible

        // ---- scores S = Q*K^T via MFMA, 10 causal tiles, write P direct ----
        for (int p = wv_; p < 10; p += NWAVES) {
            const int tm = (p >= 6) ? 3 : (p >= 3) ? 2 : (p >= 1) ? 1 : 0;
            const int sn = p - tm * (tm + 1) / 2;
            f32x4 acc = {0.f, 0.f, 0.f, 0.f};
            const int ar = tm * 16 + l15;   // q row (>=50: finite junk -> discarded)
            const int br = sn * 16 + l15;   // k row
            #pragma unroll
            for (int kk = 0; kk < 4; ++kk) {
                const int g = kk * 4 + l4;
                const short8 a  = *reinterpret_cast<const short8*>(lds + cur + RQ + ar * 128 + ((g ^ (ar & 7)) << 3));
                const short8 bb = *reinterpret_cast<const short8*>(lds + cur + RK + br * 128 + ((g ^ (br & 7)) << 3));
                acc = __builtin_amdgcn_mfma_f32_16x16x32_bf16(a, bb, acc, 0, 0, 0);
            }
            const int row0 = tm * 16 + l4 * 4;
            const int col = sn * 16 + l15;
            #pragma unroll
            for (int r = 0; r < 4; ++r) {
                const int row = row0 + r;
                lds[OP + row * 64 + (((col >> 3) ^ (row & 7)) << 3) + (col & 7)] = f2bf(acc[r]);
            }
        }
        bar_lds();   // B: P scores visible (acausal cells stale/NaN -> killed below)

        // ---- softmax: 4-lane group per row; zeros written for s>t ----
        {
            const int t = tid >> 2, ll = tid & 3;
            if (t < TT) {
                const int ga = (2 * ll) ^ (t & 7), gb = (2 * ll + 1) ^ (t & 7);
                const short8 pa = *reinterpret_cast<const short8*>(lds + OP + t * 64 + (ga << 3));
                const short8 pb = *reinterpret_cast<const short8*>(lds + OP + t * 64 + (gb << 3));
                float v[16];
                float mx = -3.4e38f;
                #pragma unroll
                for (int j = 0; j < 8; ++j) {
                    const int s = 16 * ll + j;
                    v[j] = bf2f((ushort_t)pa[j]);
                    if (s <= t) mx = fmaxf(mx, v[j]);
                }
                #pragma unroll
                for (int j = 0; j < 8; ++j) {
                    const int s = 16 * ll + 8 + j;
                    v[8 + j] = bf2f((ushort_t)pb[j]);
                    if (s <= t) mx = fmaxf(mx, v[8 + j]);
                }
                mx = fmaxf(mx, __shfl_xor(mx, 1));
                mx = fmaxf(mx, __shfl_xor(mx, 2));
                float sum = 0.f;
                #pragma unroll
                for (int j = 0; j < 16; ++j) {
                    const int s = 16 * ll + j;
                    const float e = (s <= t) ? __expf(v[j] - mx) : 0.f;
                    v[j] = e;
                    sum += e;
                }
                sum += __shfl_xor(sum, 1);
                sum += __shfl_xor(sum, 2);
                const float inv = 1.f / sum;
                short8 wa, wb;
                #pragma unroll
                for (int j = 0; j < 8; ++j) {
                    wa[j] = (short)f2bf(v[j] * inv);
                    wb[j] = (short)f2bf(v[8 + j] * inv);
                }
                *reinterpret_cast<short8*>(lds + OP + t * 64 + (ga << 3)) = wa;
                *reinterpret_cast<short8*>(lds + OP + t * 64 + (gb << 3)) = wb;
            }
        }
        bar_lds();   // C: probabilities visible

        // ---- PV: O = P*V via MFMA, 4x7 tiles, K=64 (P zero past t) ----
        {
            float* ob = oblk + (size_t)i * (TT * HH);
            for (int p = wv_; p < 28; p += NWAVES) {
                const int tm = p / 7, hn = p - tm * 7;
                f32x4 acc = {0.f, 0.f, 0.f, 0.f};
                const int ar = tm * 16 + l15;   // P row
                const int br = hn * 16 + l15;   // vT row (junk rows -> discarded h cols)
                #pragma unroll
                for (int kk = 0; kk < 2; ++kk) {
                    const int g = kk * 4 + l4;
                    const short8 a  = *reinterpret_cast<const short8*>(lds + OP + ar * 64 + ((g ^ (ar & 7)) << 3));
                    const short8 bb = *reinterpret_cast<const short8*>(lds + cur + RV + br * 64 + ((g ^ (br & 7)) << 3));
                    acc = __builtin_amdgcn_mfma_f32_16x16x32_bf16(a, bb, acc, 0, 0, 0);
                }
                const int h = hn * 16 + l15;
                const int t0 = tm * 16 + l4 * 4;
                if (h < HH) {
                    #pragma unroll
                    for (int r = 0; r < 4; ++r) {
                        const int t = t0 + r;
                        if (t < TT) ob[t * HH + h] = acc[r];
                    }
                }
            }
        }

        // ---- consume prefetch: proj(b(i+1)) into other buffer (overwrites P) ----
        if (i + 1 < NB) {
            bar_lds();   // D: P dead, all cur-buffer reads done
            do_proj(oth);
        }
    }
}

extern "C" void kernel_launch(void* const* d_in, const int* in_sizes, int n_in,
                              void* d_out, int out_size, void* d_ws, size_t ws_size,
                              hipStream_t stream) {
    const float* x  = (const float*)d_in[0];
    const float* wq = (const float*)d_in[1];
    const float* wk = (const float*)d_in[2];
    const float* wv = (const float*)d_in[3];
    float* out = (float*)d_out;
    headc_fused<<<dim3(GRID), dim3(NTHR), 0, stream>>>(x, wq, wk, wv, out);
}

// Round 12
// 121.261 us; speedup vs baseline: 1.1667x; 1.1667x over previous
//
#include <hip/hip_runtime.h>
#include <hip/hip_bf16.h>

// HeadC fused: grouped 1x1-conv projections (q,k,v) + causal softmax attention.
// B=4096, T=50, N_EMBED=600, HEAD_SIZE=100, CHUNK=6. One block per batch.
// R9: swapped-QK^T (mfma(K,Q) -> lane holds an S-row slice for one t) with
// in-register softmax (shfl over the 4 l4-lanes) and single post-softmax P
// write overlaying the dead q rows -> 2 barriers, 39.9 KB LDS. Phase 1 uses a
// 2-deep ping-pong load pipeline (xA/xB) for ~2x loads in flight.

#define BATCH 4096
#define TT 50
#define HH 100
#define CC 600

typedef __attribute__((ext_vector_type(8))) short short8;
typedef __attribute__((ext_vector_type(4))) short short4v;
typedef __attribute__((ext_vector_type(4))) float f32x4;
typedef unsigned short ushort_t;

constexpr int NTHR = 256;
constexpr int NWAVES = 4;
constexpr float kScale = 0.04082482904638630163f;  // 600^-0.5 (folded into q)

// LDS (ushort units): 19968 us = 39936 B.
//   q  @ 0      [50][128] bf16, granule XOR swizzle (row&7). After its wave's
//               B-frag reads, row t's cols 0..63 are overlaid by P[t][s].
//   k  @ 6400   [50][128]  (A-frag rows 50..63 spill into vT: junk, s>t masked)
//   vT @ 12800  [100][64]  (vT[h][t]; cols 52..63 zeroed; rows 100..111 spill
//               into pad -> junk only in discarded h>=100 D-cols)
//   pad@ 19200  768 us (junk OK)
constexpr int RQ = 0, RK = 6400, RV = 12800, LDS_US = 19968;

__device__ __forceinline__ ushort_t f2bf(float f) {
    return __builtin_bit_cast(ushort_t, __float2bfloat16(f));
}
// barrier without vmcnt drain (LDS ordering only)
__device__ __forceinline__ void bar_lds() {
    asm volatile("s_waitcnt lgkmcnt(0)" ::: "memory");
    __builtin_amdgcn_s_barrier();
    asm volatile("" ::: "memory");
}

__global__ __launch_bounds__(NTHR, 3) void headc_fused(
    const float* __restrict__ x,
    const float* __restrict__ wq,
    const float* __restrict__ wk,
    const float* __restrict__ wv,
    float* __restrict__ out)
{
    __shared__ __align__(16) ushort_t lds[LDS_US];

    const int tid = threadIdx.x;
    const int b = blockIdx.x;
    const float* xb = x + (size_t)b * (TT * CC);

    // ---- pad zeroing (concurrent with phase 1; granules disjoint from proj writes) ----
    {
        const short8 z8 = {0, 0, 0, 0, 0, 0, 0, 0};
        const short4v z4 = {0, 0, 0, 0};
        if (tid < 200) {
            if (tid < 100) {  // q/k K-pad cols 100..127 (logical granule 12-hi, 13..15)
                const int arr = tid / 50;
                const int r = tid % 50;
                const int base = (arr ? RK : RQ) + r * 128;
                *reinterpret_cast<short4v*>(lds + base + ((12 ^ (r & 7)) << 3) + 4) = z4;
                *reinterpret_cast<short8*>(lds + base + ((13 ^ (r & 7)) << 3)) = z8;
                *reinterpret_cast<short8*>(lds + base + ((14 ^ (r & 7)) << 3)) = z8;
                *reinterpret_cast<short8*>(lds + base + ((15 ^ (r & 7)) << 3)) = z8;
            } else {          // vT K-pad cols t=52..63 (granule 6-hi, 7)
                const int h = tid - 100;
                const int base = RV + h * 64;
                *reinterpret_cast<short4v*>(lds + base + ((6 ^ (h & 7)) << 3) + 4) = z4;
                *reinterpret_cast<short8*>(lds + base + ((7 ^ (h & 7)) << 3)) = z8;
            }
        }
    }

    // ---- phase 1: projections, hp pinned, 2-deep load pipeline over qd ----
    const int hp = tid % 50;
    const int c = tid / 50;            // 0..5 (c==5 inactive)
    const int h0 = hp * 2;
    const bool pactive = (tid < 250);
    const bool has3 = (c < 3);         // qd set {c, c+5} (+ {c+10} if c<3)

    if (pactive) {
        const float4 w0 = *(const float4*)(wq + h0 * 6);
        const float4 w1 = *(const float4*)(wq + h0 * 6 + 4);
        const float4 w2 = *(const float4*)(wq + h0 * 6 + 8);
        const float4 w3 = *(const float4*)(wk + h0 * 6);
        const float4 w4 = *(const float4*)(wk + h0 * 6 + 4);
        const float4 w5 = *(const float4*)(wk + h0 * 6 + 8);
        const float4 w6 = *(const float4*)(wv + h0 * 6);
        const float4 w7 = *(const float4*)(wv + h0 * 6 + 4);
        const float4 w8 = *(const float4*)(wv + h0 * 6 + 8);

        float4 xA[4][3], xB[4][3];

        auto issue = [&](float4 (&xr)[4][3], int qd) {
            const int tb = qd * 4;
            #pragma unroll
            for (int r = 0; r < 4; ++r) {
                const int tc = (tb + r < TT) ? (tb + r) : (TT - 1);
                const float* xp = xb + tc * CC + h0 * 6;   // 48B/lane, coalesced
                xr[r][0] = *(const float4*)xp;
                xr[r][1] = *(const float4*)(xp + 4);
                xr[r][2] = *(const float4*)(xp + 8);
            }
        };
        auto proj = [&](const float4 (&xr)[4][3], int qd) {
            const int tb = qd * 4;
            short4v vp0 = {0, 0, 0, 0}, vp1 = {0, 0, 0, 0};
            #pragma unroll
            for (int r = 0; r < 4; ++r) {
                const int t = tb + r;
                const float4 xa = xr[r][0], xm = xr[r][1], xc = xr[r][2];
                float q0 = xa.x*w0.x + xa.y*w0.y + xa.z*w0.z + xa.w*w0.w + xm.x*w1.x + xm.y*w1.y;
                float q1 = xm.z*w1.z + xm.w*w1.w + xc.x*w2.x + xc.y*w2.y + xc.z*w2.z + xc.w*w2.w;
                float k0 = xa.x*w3.x + xa.y*w3.y + xa.z*w3.z + xa.w*w3.w + xm.x*w4.x + xm.y*w4.y;
                float k1 = xm.z*w4.z + xm.w*w4.w + xc.x*w5.x + xc.y*w5.y + xc.z*w5.z + xc.w*w5.w;
                float v0 = xa.x*w6.x + xa.y*w6.y + xa.z*w6.z + xa.w*w6.w + xm.x*w7.x + xm.y*w7.y;
                float v1 = xm.z*w7.z + xm.w*w7.w + xc.x*w8.x + xc.y*w8.y + xc.z*w8.z + xc.w*w8.w;
                q0 *= kScale; q1 *= kScale;
                if (t < TT) {
                    const int qg = (((h0 >> 3) ^ (t & 7)) << 3) + (h0 & 7);
                    *reinterpret_cast<unsigned*>(lds + RQ + t * 128 + qg) =
                        (unsigned)f2bf(q0) | ((unsigned)f2bf(q1) << 16);
                    *reinterpret_cast<unsigned*>(lds + RK + t * 128 + qg) =
                        (unsigned)f2bf(k0) | ((unsigned)f2bf(k1) << 16);
                    vp0[r] = (short)f2bf(v0);
                    vp1[r] = (short)f2bf(v1);
                }
            }
            const int g = qd >> 1, half = (qd & 1) * 4;
            *reinterpret_cast<short4v*>(lds + RV + h0 * 64 + ((g ^ (h0 & 7)) << 3) + half) = vp0;
            *reinterpret_cast<short4v*>(lds + RV + (h0 + 1) * 64 + ((g ^ ((h0 + 1) & 7)) << 3) + half) = vp1;
        };

        issue(xA, c);
        issue(xB, c + 5);
        proj(xA, c);
        if (has3) issue(xA, c + 10);
        proj(xB, c + 5);
        if (has3) proj(xA, c + 10);
    }
    bar_lds();   // barrier 1: q,k,vT ready

    const int w = tid >> 6;
    const int lane = tid & 63;
    const int l15 = lane & 15, l4 = lane >> 4;
    const int t = w * 16 + l15;        // this lane's output row

    // ---- phase 2: S^T = K*Q^T (wave w owns t-block w; sm = 0..w), in-reg softmax,
    //      single P write overlaying dead q rows ----
    {
        // q B-frags for row t (this lane reads ONLY row t; overlaid later by P row t)
        short8 qf[4];
        #pragma unroll
        for (int kk = 0; kk < 4; ++kk)
            qf[kk] = *reinterpret_cast<const short8*>(lds + RQ + t * 128 + (((kk * 4 + l4) ^ (t & 7)) << 3));

        f32x4 sacc[4];
        #pragma unroll
        for (int sm = 0; sm < 4; ++sm) {
            f32x4 a = {0.f, 0.f, 0.f, 0.f};
            if (sm <= w) {
                const int ar = sm * 16 + l15;   // k row (s); rows>=50 junk -> masked (s>t)
                #pragma unroll
                for (int kk = 0; kk < 4; ++kk) {
                    const short8 kf = *reinterpret_cast<const short8*>(lds + RK + ar * 128 + (((kk * 4 + l4) ^ (ar & 7)) << 3));
                    a = __builtin_amdgcn_mfma_f32_16x16x32_bf16(kf, qf[kk], a, 0, 0, 0);
                }
            }
            sacc[sm] = a;   // sacc[sm][r] = S[t][sm*16 + l4*4 + r]
        }

        float mx = -3.4e38f;
        #pragma unroll
        for (int sm = 0; sm < 4; ++sm) {
            #pragma unroll
            for (int r = 0; r < 4; ++r) {
                const int s = sm * 16 + l4 * 4 + r;
                if (sm <= w && s <= t) mx = fmaxf(mx, sacc[sm][r]);
            }
        }
        mx = fmaxf(mx, __shfl_xor(mx, 16));
        mx = fmaxf(mx, __shfl_xor(mx, 32));
        float sum = 0.f;
        #pragma unroll
        for (int sm = 0; sm < 4; ++sm) {
            #pragma unroll
            for (int r = 0; r < 4; ++r) {
                const int s = sm * 16 + l4 * 4 + r;
                const float e = (sm <= w && s <= t) ? __expf(sacc[sm][r] - mx) : 0.f;
                sacc[sm][r] = e;
                sum += e;
            }
        }
        sum += __shfl_xor(sum, 16);
        sum += __shfl_xor(sum, 32);
        const float inv = 1.f / sum;

        if (t < TT) {   // t>=50 must not write (would corrupt k rows 0..13)
            #pragma unroll
            for (int sm = 0; sm < 4; ++sm) {
                #pragma unroll
                for (int rp = 0; rp < 2; ++rp) {
                    const int s0 = sm * 16 + l4 * 4 + 2 * rp;
                    const unsigned pk = (unsigned)f2bf(sacc[sm][2 * rp] * inv)
                                      | ((unsigned)f2bf(sacc[sm][2 * rp + 1] * inv) << 16);
                    *reinterpret_cast<unsigned*>(lds + RQ + t * 128 + (((s0 >> 3) ^ (t & 7)) << 3) + (s0 & 7)) = pk;
                }
            }
        }
    }
    bar_lds();   // barrier 2: P ready (q region rows t<50, cols 0..63)

    // ---- phase 3: O = P*V via MFMA, 4x7 tiles, K=64 (P zero past t) ----
    float* ob = out + (size_t)b * (TT * HH);
    for (int p = w; p < 28; p += NWAVES) {
        const int tm = p / 7, hn = p - tm * 7;
        f32x4 acc = {0.f, 0.f, 0.f, 0.f};
        const int ar = tm * 16 + l15;   // P row (rows>=50 stale-q junk -> discarded)
        const int br = hn * 16 + l15;   // vT row (h; rows>=100 junk -> discarded cols)
        #pragma unroll
        for (int kk = 0; kk < 2; ++kk) {
            const int g = kk * 4 + l4;
            const short8 a  = *reinterpret_cast<const short8*>(lds + RQ + ar * 128 + ((g ^ (ar & 7)) << 3));
            const short8 bb = *reinterpret_cast<const short8*>(lds + RV + br * 64 + ((g ^ (br & 7)) << 3));
            acc = __builtin_amdgcn_mfma_f32_16x16x32_bf16(a, bb, acc, 0, 0, 0);
        }
        const int h = hn * 16 + l15;
        const int t0 = tm * 16 + l4 * 4;
        if (h < HH) {
            #pragma unroll
            for (int r = 0; r < 4; ++r) {
                const int tt = t0 + r;
                if (tt < TT) ob[tt * HH + h] = acc[r];
            }
        }
    }
}

extern "C" void kernel_launch(void* const* d_in, const int* in_sizes, int n_in,
                              void* d_out, int out_size, void* d_ws, size_t ws_size,
                              hipStream_t stream) {
    const float* x  = (const float*)d_in[0];
    const float* wq = (const float*)d_in[1];
    const float* wk = (const float*)d_in[2];
    const float* wv = (const float*)d_in[3];
    float* out = (float*)d_out;
    headc_fused<<<dim3(BATCH), dim3(NTHR), 0, stream>>>(x, wq, wk, wv, out);
}